// Round 14
// baseline (85.650 us; speedup 1.0000x reference)
//
#include <hip/hip_runtime.h>
#include <hip/hip_bf16.h>

#define N_NODES 50000
#define E_EDGES 1600000
#define IN_F    128
#define OUT_F   64
#define ALPHA   0.2f

#define BKT_SHIFT 8
#define BKT_NODES 256
#define NBKT 196                 // ceil(50000/256)
#define BKT_CAP 16384            // per-bucket record capacity (mean 8192, 90 sigma)
#define CHUNK 4096               // edges per binning block
#define NBLK_BIN 391             // ceil(1600000/4096)
#define NBLK_GEMM 782            // ceil(50000/64)

typedef __bf16 bf16x8 __attribute__((ext_vector_type(8)));
typedef float  f32x4  __attribute__((ext_vector_type(4)));

// round-to-nearest-even f32 -> bf16 bits
__device__ __forceinline__ unsigned f32_to_bf16_bits(float f) {
    unsigned u = __float_as_uint(f);
    return (u + 0x7FFFu + ((u >> 16) & 1u)) >> 16;
}

__device__ __forceinline__ float bf_lo(unsigned u) { return __uint_as_float(u << 16); }
__device__ __forceinline__ float bf_hi(unsigned u) { return __uint_as_float(u & 0xffff0000u); }

// ---------------------------------------------------------------------------
// K0: seed bucket cursors + transpose/convert W to column-major bf16
// Wb[c][k] = bf16(W[k][c])  (64 x 128, 16KB) -> gemm fragment loads become
// one 16B load each instead of 8 scalar f32 loads.
// ---------------------------------------------------------------------------
__global__ void __launch_bounds__(256)
gat_init(const float* __restrict__ W, __hip_bfloat16* __restrict__ Wb,
         int* __restrict__ bcur) {
    int t = threadIdx.x;
    if (t < NBKT) bcur[t] = t * BKT_CAP;
    for (int i = t; i < IN_F * OUT_F; i += 256) {
        int k = i >> 6, c = i & 63;              // read W coalesced
        Wb[c * IN_F + k] = (__hip_bfloat16)W[i];
    }
}

// ---------------------------------------------------------------------------
// K1 fused: blocks [0, NBLK_GEMM) run the MFMA GEMM (h = X@W + scores);
// blocks [NBLK_GEMM, ...) run the LDS counting-sort binning.
// ---------------------------------------------------------------------------
__global__ void __launch_bounds__(256)
gat_gemm_bin(const float* __restrict__ x, const __hip_bfloat16* __restrict__ Wb,
             const float* __restrict__ a,
             __hip_bfloat16* __restrict__ hb,
             float* __restrict__ s_src, float* __restrict__ s_dst,
             const int* __restrict__ esrc, const int* __restrict__ edst,
             int* __restrict__ bcur, unsigned* __restrict__ recs_tmp) {
    if (blockIdx.x < NBLK_GEMM) {
        // ---- GEMM: one wave per 16 rows x 64 cols.
        // C/D layout: col = lane&15, row = (lane>>4)*4 + reg   [m89-verified]
        int wave = threadIdx.x >> 6;
        int lane = threadIdx.x & 63;
        int r0 = blockIdx.x * 64 + wave * 16;
        if (r0 >= N_NODES) return;                // 50000 = 781*64 + 16

        int col = lane & 15;
        int klo = (lane >> 4) * 8;

        // B fragments: one bf16x8 vector load each (Wb column-major)
        bf16x8 bw[4][4];
#pragma unroll
        for (int t = 0; t < 4; ++t)
#pragma unroll
            for (int s = 0; s < 4; ++s)
                bw[t][s] = *(const bf16x8*)(Wb + (16 * t + col) * IN_F + 32 * s + klo);

        const float* xr = x + ((size_t)(r0 + col)) * IN_F;
        bf16x8 aw[4];
#pragma unroll
        for (int s = 0; s < 4; ++s) {
            float4 v0 = *(const float4*)(xr + 32 * s + klo);
            float4 v1 = *(const float4*)(xr + 32 * s + klo + 4);
            aw[s][0] = (__bf16)v0.x; aw[s][1] = (__bf16)v0.y;
            aw[s][2] = (__bf16)v0.z; aw[s][3] = (__bf16)v0.w;
            aw[s][4] = (__bf16)v1.x; aw[s][5] = (__bf16)v1.y;
            aw[s][6] = (__bf16)v1.z; aw[s][7] = (__bf16)v1.w;
        }

        f32x4 acc0 = {0.f,0.f,0.f,0.f}, acc1 = {0.f,0.f,0.f,0.f};
        f32x4 acc2 = {0.f,0.f,0.f,0.f}, acc3 = {0.f,0.f,0.f,0.f};
#pragma unroll
        for (int s = 0; s < 4; ++s) {
            acc0 = __builtin_amdgcn_mfma_f32_16x16x32_bf16(aw[s], bw[0][s], acc0, 0, 0, 0);
            acc1 = __builtin_amdgcn_mfma_f32_16x16x32_bf16(aw[s], bw[1][s], acc1, 0, 0, 0);
            acc2 = __builtin_amdgcn_mfma_f32_16x16x32_bf16(aw[s], bw[2][s], acc2, 0, 0, 0);
            acc3 = __builtin_amdgcn_mfma_f32_16x16x32_bf16(aw[s], bw[3][s], acc3, 0, 0, 0);
        }

        int grp = lane >> 4;
#pragma unroll
        for (int reg = 0; reg < 4; ++reg) {
            size_t base = (size_t)(r0 + grp * 4 + reg) * OUT_F + col;
            hb[base +  0] = __float2bfloat16(acc0[reg]);
            hb[base + 16] = __float2bfloat16(acc1[reg]);
            hb[base + 32] = __float2bfloat16(acc2[reg]);
            hb[base + 48] = __float2bfloat16(acc3[reg]);
        }

        float as0 = a[col], as1 = a[16 + col], as2 = a[32 + col], as3 = a[48 + col];
        float ad0 = a[64 + col], ad1 = a[80 + col], ad2 = a[96 + col], ad3 = a[112 + col];
#pragma unroll
        for (int reg = 0; reg < 4; ++reg) {
            float ps = acc0[reg] * as0 + acc1[reg] * as1 + acc2[reg] * as2 + acc3[reg] * as3;
            float pd = acc0[reg] * ad0 + acc1[reg] * ad1 + acc2[reg] * ad2 + acc3[reg] * ad3;
#pragma unroll
            for (int off = 1; off < 16; off <<= 1) {
                ps += __shfl_xor(ps, off, 64);
                pd += __shfl_xor(pd, off, 64);
            }
            if (col == 0) {
                s_src[r0 + grp * 4 + reg] = ps;
                s_dst[r0 + grp * 4 + reg] = pd;
            }
        }
    } else {
        // ---- BIN: LDS counting-sort of CHUNK edges by bucket (src>>8).
        // Edge loads vectorized: int4 = 4 edges per load.
        __shared__ unsigned recs_l[CHUNK];     // 16KB
        __shared__ int cnt[NBKT];
        __shared__ int start[256];
        __shared__ int gbase[NBKT];
        __shared__ int sc[256];

        int t = threadIdx.x;
        int blkbin = blockIdx.x - NBLK_GEMM;
        int ebase = blkbin * CHUNK;
        const int4* esrc4 = (const int4*)esrc;
        const int4* edst4 = (const int4*)edst;

        if (t < NBKT) cnt[t] = 0;
        __syncthreads();

        unsigned rec[16];
        int      loc[16];
#pragma unroll
        for (int k4 = 0; k4 < 4; ++k4) {
            int e4 = blkbin * (CHUNK / 4) + k4 * 256 + t;
            if (e4 < E_EDGES / 4) {
                int4 sv = esrc4[e4];
                int4 dv = edst4[e4];
                rec[k4*4+0] = ((unsigned)sv.x << 16) | (unsigned)dv.x;
                rec[k4*4+1] = ((unsigned)sv.y << 16) | (unsigned)dv.y;
                rec[k4*4+2] = ((unsigned)sv.z << 16) | (unsigned)dv.z;
                rec[k4*4+3] = ((unsigned)sv.w << 16) | (unsigned)dv.w;
                loc[k4*4+0] = atomicAdd(&cnt[(unsigned)sv.x >> BKT_SHIFT], 1);
                loc[k4*4+1] = atomicAdd(&cnt[(unsigned)sv.y >> BKT_SHIFT], 1);
                loc[k4*4+2] = atomicAdd(&cnt[(unsigned)sv.z >> BKT_SHIFT], 1);
                loc[k4*4+3] = atomicAdd(&cnt[(unsigned)sv.w >> BKT_SHIFT], 1);
            } else {
                loc[k4*4+0] = loc[k4*4+1] = loc[k4*4+2] = loc[k4*4+3] = -1;
                rec[k4*4+0] = rec[k4*4+1] = rec[k4*4+2] = rec[k4*4+3] = 0;
            }
        }
        __syncthreads();

        int v = (t < NBKT) ? cnt[t] : 0;
        sc[t] = v;
        __syncthreads();
        for (int d = 1; d < 256; d <<= 1) {
            int add = (t >= d) ? sc[t - d] : 0;
            __syncthreads();
            sc[t] += add;
            __syncthreads();
        }
        start[t] = sc[t] - v;
        __syncthreads();

#pragma unroll
        for (int k = 0; k < 16; ++k)
            if (loc[k] >= 0)
                recs_l[start[rec[k] >> 24] + loc[k]] = rec[k];

        if (t < NBKT) {
            int c = cnt[t];
            gbase[t] = (c > 0) ? atomicAdd(&bcur[t], c) : 0;
        }
        __syncthreads();

        int total = min(CHUNK, E_EDGES - ebase);
        for (int i = t; i < total; i += 256) {
            unsigned r = recs_l[i];
            int b = r >> 24;
            int pos = gbase[b] + (i - start[b]);
            if (pos < (b + 1) * BKT_CAP)           // 90-sigma guard, never trips
                recs_tmp[pos] = r;
        }
    }
}

// ---------------------------------------------------------------------------
// K3: per-bucket pass, 1024 threads: LDS histogram -> rowptr/dcnt, then
// compute ee and place 4B records {dst:16 | ee:bf16} sorted-by-src.
// Streaming loads vectorized (uint4 = 4 records).
// ---------------------------------------------------------------------------
__global__ void __launch_bounds__(1024)
gat_pass2(const int* __restrict__ bcur, const unsigned* __restrict__ recs_tmp,
          const float* __restrict__ s_src, const float* __restrict__ s_dst,
          int* __restrict__ rowptr, int* __restrict__ dcnt,
          unsigned* __restrict__ recs) {
    __shared__ int ncnt[256];
    __shared__ int lcur[256];
    __shared__ int sc[256];

    int b = blockIdx.x;
    int t = threadIdx.x;
    int nbase = b << BKT_SHIFT;
    int rbase = b * BKT_CAP;
    int m = bcur[b] - rbase;                       // records in this bucket
    const uint4* rt4 = (const uint4*)(recs_tmp + rbase);
    int m4 = m >> 2;

    if (t < 256) ncnt[t] = 0;
    __syncthreads();

    for (int i = t; i < m4; i += 1024) {
        uint4 r = rt4[i];
        atomicAdd(&ncnt[(r.x >> 16) & (BKT_NODES - 1)], 1);
        atomicAdd(&ncnt[(r.y >> 16) & (BKT_NODES - 1)], 1);
        atomicAdd(&ncnt[(r.z >> 16) & (BKT_NODES - 1)], 1);
        atomicAdd(&ncnt[(r.w >> 16) & (BKT_NODES - 1)], 1);
    }
    for (int i = (m4 << 2) + t; i < m; i += 1024) {
        unsigned r = recs_tmp[rbase + i];
        atomicAdd(&ncnt[(r >> 16) & (BKT_NODES - 1)], 1);
    }
    __syncthreads();

    int v = 0;
    if (t < 256) { v = ncnt[t]; sc[t] = v; }
    __syncthreads();
    for (int d = 1; d < 256; d <<= 1) {
        int add = 0;
        if (t < 256 && t >= d) add = sc[t - d];
        __syncthreads();
        if (t < 256) sc[t] += add;
        __syncthreads();
    }
    if (t < 256) {
        int nstart = sc[t] - v;
        lcur[t] = nstart;
        int node = nbase + t;
        if (node < N_NODES) {
            rowptr[node] = rbase + nstart;
            dcnt[node]   = v;
        }
    }
    __syncthreads();

    for (int i = t; i < m4; i += 1024) {
        uint4 r4 = rt4[i];
#pragma unroll
        for (int jj = 0; jj < 4; ++jj) {
            unsigned r = (&r4.x)[jj];
            int s = r >> 16;
            int d = r & 0xFFFF;
            float sco = s_src[s] + s_dst[d];
            float lr = sco > 0.f ? sco : ALPHA * sco;
            float ee = __expf(-lr);
            int idx = atomicAdd(&lcur[s & (BKT_NODES - 1)], 1);
            recs[rbase + idx] = ((unsigned)d << 16) | f32_to_bf16_bits(ee);
        }
    }
    for (int i = (m4 << 2) + t; i < m; i += 1024) {
        unsigned r = recs_tmp[rbase + i];
        int s = r >> 16;
        int d = r & 0xFFFF;
        float sco = s_src[s] + s_dst[d];
        float lr = sco > 0.f ? sco : ALPHA * sco;
        float ee = __expf(-lr);
        int idx = atomicAdd(&lcur[s & (BKT_NODES - 1)], 1);
        recs[rbase + idx] = ((unsigned)d << 16) | f32_to_bf16_bits(ee);
    }
}

// ---------------------------------------------------------------------------
// K4: pair-node half-wave aggregate (R12-proven). Lanes 0-31 -> node 2p,
// lanes 32-63 -> node 2p+1; four 8-lane groups per half, uint4 per lane
// (8 lanes x 16B = full 128B row). Full 32-record batches run an
// unguarded constant-trip loop; guarded tail only for the last batch.
// ---------------------------------------------------------------------------
__global__ void __launch_bounds__(256)
gat_aggregate(const int* __restrict__ rowptr, const int* __restrict__ dcnt,
              const unsigned* __restrict__ recs,
              const __hip_bfloat16* __restrict__ hb, float* __restrict__ out) {
    int pair = blockIdx.x * 4 + (threadIdx.x >> 6);   // 6250 blocks exact
    int lane = threadIdx.x & 63;
    int h    = lane >> 5;            // half -> node selector
    int l    = lane & 31;            // lane within half
    int g2   = l >> 3;               // 8-lane edge group 0..3
    int c8   = l & 7;                // feature octet: feats 8*c8 .. 8*c8+7
    int node = pair * 2 + h;
    int beg = rowptr[node];
    int n   = dcnt[node];
    const uint4* hb4 = (const uint4*)hb;   // row = dst*8 + c8 (16B granules)

    float a0=0.f,a1=0.f,a2=0.f,a3=0.f,a4=0.f,a5=0.f,a6=0.f,a7=0.f, rs=0.f;

    unsigned rec = 0;
    if (l < n) rec = recs[beg + l];                   // stage batch 0
    int base = 0;
    for (; base + 32 <= n; base += 32) {              // full batches: no guards
        unsigned rec_next = 0;
        int nb = base + 32;
        if (nb < n && l < n - nb) rec_next = recs[beg + nb + l];
#pragma unroll
        for (int k = 0; k < 8; ++k) {
            int j = g2 * 8 + k;
            unsigned r = (unsigned)__shfl((int)rec, h * 32 + j, 64);
            float ee = __uint_as_float((r & 0xFFFFu) << 16);
            uint4 u = hb4[(r >> 16) * 8 + c8];
            a0 += ee * bf_lo(u.x); a1 += ee * bf_hi(u.x);
            a2 += ee * bf_lo(u.y); a3 += ee * bf_hi(u.y);
            a4 += ee * bf_lo(u.z); a5 += ee * bf_hi(u.z);
            a6 += ee * bf_lo(u.w); a7 += ee * bf_hi(u.w);
            rs += ee;
        }
        rec = rec_next;
    }
    if (base < n) {                                   // tail batch, m < 32
        int m = n - base;
        int nq = (m + 3) >> 2;
#pragma unroll 8
        for (int k = 0; k < nq; ++k) {
            int j = g2 * nq + k;
            unsigned r = (unsigned)__shfl((int)rec, h * 32 + j, 64);
            float ee = (j < m) ? __uint_as_float((r & 0xFFFFu) << 16) : 0.f;
            uint4 u = hb4[(r >> 16) * 8 + c8];
            a0 += ee * bf_lo(u.x); a1 += ee * bf_hi(u.x);
            a2 += ee * bf_lo(u.y); a3 += ee * bf_hi(u.y);
            a4 += ee * bf_lo(u.z); a5 += ee * bf_hi(u.z);
            a6 += ee * bf_lo(u.w); a7 += ee * bf_hi(u.w);
            rs += ee;
        }
    }

    // merge 8-lane groups within the half: xor 8 then 16 (never crosses 32)
#pragma unroll
    for (int off = 8; off <= 16; off <<= 1) {
        a0 += __shfl_xor(a0, off, 64); a1 += __shfl_xor(a1, off, 64);
        a2 += __shfl_xor(a2, off, 64); a3 += __shfl_xor(a3, off, 64);
        a4 += __shfl_xor(a4, off, 64); a5 += __shfl_xor(a5, off, 64);
        a6 += __shfl_xor(a6, off, 64); a7 += __shfl_xor(a7, off, 64);
        rs += __shfl_xor(rs, off, 64);
    }

    if (g2 == 0) {
        float inv = (rs != 0.f) ? 1.f / rs : 0.f;
        float v0 = a0 * inv, v1 = a1 * inv, v2 = a2 * inv, v3 = a3 * inv;
        float v4 = a4 * inv, v5 = a5 * inv, v6 = a6 * inv, v7 = a7 * inv;
        v0 = v0 > 0.f ? v0 : (__expf(v0) - 1.f);
        v1 = v1 > 0.f ? v1 : (__expf(v1) - 1.f);
        v2 = v2 > 0.f ? v2 : (__expf(v2) - 1.f);
        v3 = v3 > 0.f ? v3 : (__expf(v3) - 1.f);
        v4 = v4 > 0.f ? v4 : (__expf(v4) - 1.f);
        v5 = v5 > 0.f ? v5 : (__expf(v5) - 1.f);
        v6 = v6 > 0.f ? v6 : (__expf(v6) - 1.f);
        v7 = v7 > 0.f ? v7 : (__expf(v7) - 1.f);
        float* o = out + (size_t)node * OUT_F + 8 * c8;
        *(float4*)(o)     = make_float4(v0, v1, v2, v3);
        *(float4*)(o + 4) = make_float4(v4, v5, v6, v7);
    }
}

// ---------------------------------------------------------------------------
extern "C" void kernel_launch(void* const* d_in, const int* in_sizes, int n_in,
                              void* d_out, int out_size, void* d_ws, size_t ws_size,
                              hipStream_t stream) {
    const float* x    = (const float*)d_in[0];
    const int*   edge = (const int*)d_in[1];   // (2, E) int32 row-major
    const float* W    = (const float*)d_in[2];
    const float* a    = (const float*)d_in[3];
    float*       out  = (float*)d_out;

    const int* esrc = edge;
    const int* edst = edge + E_EDGES;

    char* ws = (char*)d_ws;
    size_t off = 0;
    __hip_bfloat16* hb = (__hip_bfloat16*)(ws + off); off += (size_t)N_NODES * OUT_F * 2; // 6.4MB
    __hip_bfloat16* Wb = (__hip_bfloat16*)(ws + off); off += (size_t)IN_F * OUT_F * 2;    // 16KB
    float* s_src  = (float*)(ws + off); off += (size_t)N_NODES * 4;
    float* s_dst  = (float*)(ws + off); off += (size_t)N_NODES * 4;
    int*   rowptr = (int*)  (ws + off); off += (size_t)N_NODES * 4;
    int*   dcnt   = (int*)  (ws + off); off += (size_t)N_NODES * 4;
    int*   bcur   = (int*)  (ws + off); off += 256 * 4;
    unsigned* recs_tmp = (unsigned*)(ws + off); off += (size_t)NBKT * BKT_CAP * 4;  // 12.8MB
    unsigned* recs     = (unsigned*)(ws + off); off += (size_t)NBKT * BKT_CAP * 4;  // 12.8MB

    gat_init<<<1, 256, 0, stream>>>(W, Wb, bcur);

    gat_gemm_bin<<<NBLK_GEMM + NBLK_BIN, 256, 0, stream>>>(
        x, Wb, a, hb, s_src, s_dst, esrc, edst, bcur, recs_tmp);

    gat_pass2<<<NBKT, 1024, 0, stream>>>(bcur, recs_tmp, s_src, s_dst,
                                         rowptr, dcnt, recs);

    gat_aggregate<<<N_NODES / 8, 256, 0, stream>>>(rowptr, dcnt, recs, hb, out);
}

// Round 15
// 76.618 us; speedup vs baseline: 1.1179x; 1.1179x over previous
//
#include <hip/hip_runtime.h>
#include <hip/hip_bf16.h>

#define N_NODES 50000
#define E_EDGES 1600000
#define IN_F    128
#define OUT_F   64
#define ALPHA   0.2f

#define BKT_SHIFT 8
#define BKT_NODES 256
#define NBKT 196                 // ceil(50000/256)
#define BKT_CAP 16384            // per-bucket record capacity (mean 8192, 90 sigma)
#define CHUNK 4096               // edges per binning block
#define NBLK_BIN 391             // ceil(1600000/4096)
#define NBLK_GEMM 782            // ceil(50000/64)

typedef __bf16 bf16x8 __attribute__((ext_vector_type(8)));
typedef float  f32x4  __attribute__((ext_vector_type(4)));

// round-to-nearest-even f32 -> bf16 bits
__device__ __forceinline__ unsigned f32_to_bf16_bits(float f) {
    unsigned u = __float_as_uint(f);
    return (u + 0x7FFFu + ((u >> 16) & 1u)) >> 16;
}

__device__ __forceinline__ float bf_lo(unsigned u) { return __uint_as_float(u << 16); }
__device__ __forceinline__ float bf_hi(unsigned u) { return __uint_as_float(u & 0xffff0000u); }

// ---------------------------------------------------------------------------
// K1 fused: blocks [0, NBLK_GEMM) run the MFMA GEMM (h = X@W + scores);
// blocks [NBLK_GEMM, ...) run the LDS counting-sort binning.
// ---------------------------------------------------------------------------
__global__ void __launch_bounds__(256)
gat_gemm_bin(const float* __restrict__ x, const float* __restrict__ W,
             const float* __restrict__ a,
             __hip_bfloat16* __restrict__ hb,
             float* __restrict__ s_src, float* __restrict__ s_dst,
             const int* __restrict__ esrc, const int* __restrict__ edst,
             int* __restrict__ bcur, unsigned* __restrict__ recs_tmp) {
    if (blockIdx.x < NBLK_GEMM) {
        // ---- GEMM: one wave per 16 rows x 64 cols.
        // C/D layout: col = lane&15, row = (lane>>4)*4 + reg   [m89-verified]
        int wave = threadIdx.x >> 6;
        int lane = threadIdx.x & 63;
        int r0 = blockIdx.x * 64 + wave * 16;
        if (r0 >= N_NODES) return;                // 50000 = 781*64 + 16

        int col = lane & 15;
        int klo = (lane >> 4) * 8;

        bf16x8 bw[4][4];
#pragma unroll
        for (int t = 0; t < 4; ++t)
#pragma unroll
            for (int s = 0; s < 4; ++s)
#pragma unroll
                for (int j = 0; j < 8; ++j)
                    bw[t][s][j] = (__bf16)W[(32 * s + klo + j) * OUT_F + 16 * t + col];

        const float* xr = x + ((size_t)(r0 + col)) * IN_F;
        bf16x8 aw[4];
#pragma unroll
        for (int s = 0; s < 4; ++s) {
            float4 v0 = *(const float4*)(xr + 32 * s + klo);
            float4 v1 = *(const float4*)(xr + 32 * s + klo + 4);
            aw[s][0] = (__bf16)v0.x; aw[s][1] = (__bf16)v0.y;
            aw[s][2] = (__bf16)v0.z; aw[s][3] = (__bf16)v0.w;
            aw[s][4] = (__bf16)v1.x; aw[s][5] = (__bf16)v1.y;
            aw[s][6] = (__bf16)v1.z; aw[s][7] = (__bf16)v1.w;
        }

        f32x4 acc0 = {0.f,0.f,0.f,0.f}, acc1 = {0.f,0.f,0.f,0.f};
        f32x4 acc2 = {0.f,0.f,0.f,0.f}, acc3 = {0.f,0.f,0.f,0.f};
#pragma unroll
        for (int s = 0; s < 4; ++s) {
            acc0 = __builtin_amdgcn_mfma_f32_16x16x32_bf16(aw[s], bw[0][s], acc0, 0, 0, 0);
            acc1 = __builtin_amdgcn_mfma_f32_16x16x32_bf16(aw[s], bw[1][s], acc1, 0, 0, 0);
            acc2 = __builtin_amdgcn_mfma_f32_16x16x32_bf16(aw[s], bw[2][s], acc2, 0, 0, 0);
            acc3 = __builtin_amdgcn_mfma_f32_16x16x32_bf16(aw[s], bw[3][s], acc3, 0, 0, 0);
        }

        int grp = lane >> 4;
#pragma unroll
        for (int reg = 0; reg < 4; ++reg) {
            size_t base = (size_t)(r0 + grp * 4 + reg) * OUT_F + col;
            hb[base +  0] = __float2bfloat16(acc0[reg]);
            hb[base + 16] = __float2bfloat16(acc1[reg]);
            hb[base + 32] = __float2bfloat16(acc2[reg]);
            hb[base + 48] = __float2bfloat16(acc3[reg]);
        }

        float as0 = a[col], as1 = a[16 + col], as2 = a[32 + col], as3 = a[48 + col];
        float ad0 = a[64 + col], ad1 = a[80 + col], ad2 = a[96 + col], ad3 = a[112 + col];
#pragma unroll
        for (int reg = 0; reg < 4; ++reg) {
            float ps = acc0[reg] * as0 + acc1[reg] * as1 + acc2[reg] * as2 + acc3[reg] * as3;
            float pd = acc0[reg] * ad0 + acc1[reg] * ad1 + acc2[reg] * ad2 + acc3[reg] * ad3;
#pragma unroll
            for (int off = 1; off < 16; off <<= 1) {
                ps += __shfl_xor(ps, off, 64);
                pd += __shfl_xor(pd, off, 64);
            }
            if (col == 0) {
                s_src[r0 + grp * 4 + reg] = ps;
                s_dst[r0 + grp * 4 + reg] = pd;
            }
        }
    } else {
        // ---- BIN: LDS counting-sort of CHUNK edges by bucket (src>>8).
        __shared__ unsigned recs_l[CHUNK];     // 16KB
        __shared__ int cnt[NBKT];
        __shared__ int start[256];
        __shared__ int gbase[NBKT];
        __shared__ int sc[256];

        int t = threadIdx.x;
        int ebase = (blockIdx.x - NBLK_GEMM) * CHUNK;

        if (t < NBKT) cnt[t] = 0;
        __syncthreads();

        unsigned rec[16];
        int      loc[16];
#pragma unroll
        for (int k = 0; k < 16; ++k) {
            int e = ebase + k * 256 + t;
            if (e < E_EDGES) {
                unsigned s = (unsigned)esrc[e];
                unsigned d = (unsigned)edst[e];
                rec[k] = (s << 16) | d;
                loc[k] = atomicAdd(&cnt[s >> BKT_SHIFT], 1);
            } else {
                loc[k] = -1;
                rec[k] = 0;
            }
        }
        __syncthreads();

        int v = (t < NBKT) ? cnt[t] : 0;
        sc[t] = v;
        __syncthreads();
        for (int d = 1; d < 256; d <<= 1) {
            int add = (t >= d) ? sc[t - d] : 0;
            __syncthreads();
            sc[t] += add;
            __syncthreads();
        }
        start[t] = sc[t] - v;
        __syncthreads();

#pragma unroll
        for (int k = 0; k < 16; ++k)
            if (loc[k] >= 0)
                recs_l[start[rec[k] >> 24] + loc[k]] = rec[k];

        if (t < NBKT) {
            int c = cnt[t];
            gbase[t] = (c > 0) ? atomicAdd(&bcur[t], c) : 0;
        }
        __syncthreads();

        int total = min(CHUNK, E_EDGES - ebase);
        for (int i = t; i < total; i += 256) {
            unsigned r = recs_l[i];
            int b = r >> 24;
            int pos = gbase[b] + (i - start[b]);
            if (pos < (b + 1) * BKT_CAP)           // 90-sigma guard, never trips
                recs_tmp[pos] = r;
        }
    }
}

// ---------------------------------------------------------------------------
// K0: seed bucket cursors at fixed-stride region bases
// ---------------------------------------------------------------------------
__global__ void __launch_bounds__(256)
gat_init_cursors(int* __restrict__ bcur) {
    int t = threadIdx.x;
    if (t < NBKT) bcur[t] = t * BKT_CAP;
}

// ---------------------------------------------------------------------------
// K3: per-bucket pass, 1024 threads: LDS histogram -> rowptr/dcnt, then
// compute ee and place 4B records {dst:16 | ee:bf16} sorted-by-src.
// ---------------------------------------------------------------------------
__global__ void __launch_bounds__(1024)
gat_pass2(const int* __restrict__ bcur, const unsigned* __restrict__ recs_tmp,
          const float* __restrict__ s_src, const float* __restrict__ s_dst,
          int* __restrict__ rowptr, int* __restrict__ dcnt,
          unsigned* __restrict__ recs) {
    __shared__ int ncnt[256];
    __shared__ int lcur[256];
    __shared__ int sc[256];

    int b = blockIdx.x;
    int t = threadIdx.x;
    int nbase = b << BKT_SHIFT;
    int rbase = b * BKT_CAP;
    int m = bcur[b] - rbase;                       // records in this bucket

    if (t < 256) ncnt[t] = 0;
    __syncthreads();

    for (int i = t; i < m; i += 1024) {
        unsigned r = recs_tmp[rbase + i];
        atomicAdd(&ncnt[(r >> 16) & (BKT_NODES - 1)], 1);
    }
    __syncthreads();

    int v = 0;
    if (t < 256) { v = ncnt[t]; sc[t] = v; }
    __syncthreads();
    for (int d = 1; d < 256; d <<= 1) {
        int add = 0;
        if (t < 256 && t >= d) add = sc[t - d];
        __syncthreads();
        if (t < 256) sc[t] += add;
        __syncthreads();
    }
    if (t < 256) {
        int nstart = sc[t] - v;
        lcur[t] = nstart;
        int node = nbase + t;
        if (node < N_NODES) {
            rowptr[node] = rbase + nstart;
            dcnt[node]   = v;
        }
    }
    __syncthreads();

    for (int i = t; i < m; i += 1024) {
        unsigned r = recs_tmp[rbase + i];
        int s = r >> 16;
        int d = r & 0xFFFF;
        float sco = s_src[s] + s_dst[d];
        float lr = sco > 0.f ? sco : ALPHA * sco;
        float ee = __expf(-lr);
        int idx = atomicAdd(&lcur[s & (BKT_NODES - 1)], 1);
        recs[rbase + idx] = ((unsigned)d << 16) | f32_to_bf16_bits(ee);
    }
}

// ---------------------------------------------------------------------------
// K4: pair-node half-wave aggregate. Lanes 0-31 -> node 2p, lanes 32-63 ->
// node 2p+1: two independent gather chains per wave (2x outstanding misses
// for the typical deg-32 node). Within a half, four 8-lane groups each
// handle one edge via uint4 (8 lanes x 16B = full 128B row). Records
// register-staged 32/node/batch with next-batch prefetch; one shfl per
// edge-group. Merge via shfl_xor(8,16) (stays within half).
// ---------------------------------------------------------------------------
__global__ void __launch_bounds__(256)
gat_aggregate(const int* __restrict__ rowptr, const int* __restrict__ dcnt,
              const unsigned* __restrict__ recs,
              const __hip_bfloat16* __restrict__ hb, float* __restrict__ out) {
    int pair = blockIdx.x * 4 + (threadIdx.x >> 6);   // 6250 blocks exact
    int lane = threadIdx.x & 63;
    int h    = lane >> 5;            // half -> node selector
    int l    = lane & 31;            // lane within half
    int g2   = l >> 3;               // 8-lane edge group 0..3
    int c8   = l & 7;                // feature octet: feats 8*c8 .. 8*c8+7
    int node = pair * 2 + h;
    int beg = rowptr[node];
    int n   = dcnt[node];
    const uint4* hb4 = (const uint4*)hb;   // row = dst*8 + c8 (16B granules)

    float a0=0.f,a1=0.f,a2=0.f,a3=0.f,a4=0.f,a5=0.f,a6=0.f,a7=0.f, rs=0.f;

    unsigned rec = 0;
    if (l < n) rec = recs[beg + l];                   // stage batch 0
    for (int base = 0; base < n; base += 32) {
        int m = n - base; if (m > 32) m = 32;
        unsigned rec_next = 0;                        // prefetch batch+1
        int nb = base + 32;
        if (nb < n && l < n - nb) rec_next = recs[beg + nb + l];
        int nq = (m + 3) >> 2;                        // edges per 8-lane group
#pragma unroll 8
        for (int k = 0; k < nq; ++k) {
            int j = g2 * nq + k;                      // this group's edge
            unsigned r = (unsigned)__shfl((int)rec, h * 32 + j, 64);
            float ee = (j < m) ? __uint_as_float((r & 0xFFFFu) << 16) : 0.f;
            uint4 u = hb4[(r >> 16) * 8 + c8];
            a0 += ee * bf_lo(u.x); a1 += ee * bf_hi(u.x);
            a2 += ee * bf_lo(u.y); a3 += ee * bf_hi(u.y);
            a4 += ee * bf_lo(u.z); a5 += ee * bf_hi(u.z);
            a6 += ee * bf_lo(u.w); a7 += ee * bf_hi(u.w);
            rs += ee;
        }
        rec = rec_next;
    }

    // merge 8-lane groups within the half: xor 8 then 16 (never crosses 32)
#pragma unroll
    for (int off = 8; off <= 16; off <<= 1) {
        a0 += __shfl_xor(a0, off, 64); a1 += __shfl_xor(a1, off, 64);
        a2 += __shfl_xor(a2, off, 64); a3 += __shfl_xor(a3, off, 64);
        a4 += __shfl_xor(a4, off, 64); a5 += __shfl_xor(a5, off, 64);
        a6 += __shfl_xor(a6, off, 64); a7 += __shfl_xor(a7, off, 64);
        rs += __shfl_xor(rs, off, 64);
    }

    if (g2 == 0) {
        float inv = (rs != 0.f) ? 1.f / rs : 0.f;
        float v0 = a0 * inv, v1 = a1 * inv, v2 = a2 * inv, v3 = a3 * inv;
        float v4 = a4 * inv, v5 = a5 * inv, v6 = a6 * inv, v7 = a7 * inv;
        v0 = v0 > 0.f ? v0 : (__expf(v0) - 1.f);
        v1 = v1 > 0.f ? v1 : (__expf(v1) - 1.f);
        v2 = v2 > 0.f ? v2 : (__expf(v2) - 1.f);
        v3 = v3 > 0.f ? v3 : (__expf(v3) - 1.f);
        v4 = v4 > 0.f ? v4 : (__expf(v4) - 1.f);
        v5 = v5 > 0.f ? v5 : (__expf(v5) - 1.f);
        v6 = v6 > 0.f ? v6 : (__expf(v6) - 1.f);
        v7 = v7 > 0.f ? v7 : (__expf(v7) - 1.f);
        float* o = out + (size_t)node * OUT_F + 8 * c8;
        *(float4*)(o)     = make_float4(v0, v1, v2, v3);
        *(float4*)(o + 4) = make_float4(v4, v5, v6, v7);
    }
}

// ---------------------------------------------------------------------------
extern "C" void kernel_launch(void* const* d_in, const int* in_sizes, int n_in,
                              void* d_out, int out_size, void* d_ws, size_t ws_size,
                              hipStream_t stream) {
    const float* x    = (const float*)d_in[0];
    const int*   edge = (const int*)d_in[1];   // (2, E) int32 row-major
    const float* W    = (const float*)d_in[2];
    const float* a    = (const float*)d_in[3];
    float*       out  = (float*)d_out;

    const int* esrc = edge;
    const int* edst = edge + E_EDGES;

    char* ws = (char*)d_ws;
    size_t off = 0;
    __hip_bfloat16* hb = (__hip_bfloat16*)(ws + off); off += (size_t)N_NODES * OUT_F * 2; // 6.4MB
    float* s_src  = (float*)(ws + off); off += (size_t)N_NODES * 4;
    float* s_dst  = (float*)(ws + off); off += (size_t)N_NODES * 4;
    int*   rowptr = (int*)  (ws + off); off += (size_t)N_NODES * 4;
    int*   dcnt   = (int*)  (ws + off); off += (size_t)N_NODES * 4;
    int*   bcur   = (int*)  (ws + off); off += 256 * 4;
    unsigned* recs_tmp = (unsigned*)(ws + off); off += (size_t)NBKT * BKT_CAP * 4;  // 12.8MB
    unsigned* recs     = (unsigned*)(ws + off); off += (size_t)NBKT * BKT_CAP * 4;  // 12.8MB

    gat_init_cursors<<<1, 256, 0, stream>>>(bcur);

    gat_gemm_bin<<<NBLK_GEMM + NBLK_BIN, 256, 0, stream>>>(
        x, W, a, hb, s_src, s_dst, esrc, edst, bcur, recs_tmp);

    gat_pass2<<<NBKT, 1024, 0, stream>>>(bcur, recs_tmp, s_src, s_dst,
                                         rowptr, dcnt, recs);

    gat_aggregate<<<N_NODES / 8, 256, 0, stream>>>(rowptr, dcnt, recs, hb, out);
}